// Round 2
// baseline (337.220 us; speedup 1.0000x reference)
//
#include <hip/hip_runtime.h>
#include <math.h>

#define TT 4096          // signal length
#define NN 8192          // padded length
#define NF 4096          // FFT length = 16^3
#define PAD(i) ((i) + 3 * ((i) >> 5))
#define LDSN 4480        // PAD(4095)=4476, rounded up; float2 -> 35840 B

// -------------------- register DFT16 (two radix-4 layers, DIT) --------------
// S = -1: forward (e^{-i}), S = +1: inverse (e^{+i}).
template<int S>
__device__ __forceinline__ void dft4(float& ar, float& ai, float& br, float& bi,
                                     float& cr, float& ci, float& er, float& ei) {
    float t0r = ar + cr, t0i = ai + ci;
    float t1r = ar - cr, t1i = ai - ci;
    float t2r = br + er, t2i = bi + ei;
    float t3r = br - er, t3i = bi - ei;
    ar = t0r + t2r; ai = t0i + t2i;
    cr = t0r - t2r; ci = t0i - t2i;
    // y1 = t1 + S*i*t3, y3 = t1 - S*i*t3
    br = t1r - S * t3i; bi = t1i + S * t3r;
    er = t1r + S * t3i; ei = t1i - S * t3r;
}

template<int S>
__device__ __forceinline__ void dft16(float xr[16], float xi[16]) {
    // layer A: DFT4 over n1 of x[n0 + 4*n1]; result A_{n0}[k0] lands at n0 + 4*k0
    #pragma unroll
    for (int n0 = 0; n0 < 4; ++n0)
        dft4<S>(xr[n0], xi[n0], xr[n0 + 4], xi[n0 + 4],
                xr[n0 + 8], xi[n0 + 8], xr[n0 + 12], xi[n0 + 12]);

    const float C1 = 0.9238795325112867f;   // cos(pi/8)
    const float S1 = 0.3826834323650898f;   // sin(pi/8)
    const float R2 = 0.7071067811865476f;
    // B_{n0}[k0] = A * W16^{S-signed n0*k0}; W^p = (cos, S*sin), theta = 2*pi*p/16
    #define TMUL(idx, wr, wi) { float _r = xr[idx]*(wr) - xi[idx]*(wi); \
                                xi[idx] = xr[idx]*(wi) + xi[idx]*(wr); xr[idx] = _r; }
    TMUL(5,  C1,  S * S1)     // p=1
    TMUL(9,  R2,  S * R2)     // p=2
    TMUL(13, S1,  S * C1)     // p=3
    TMUL(6,  R2,  S * R2)     // p=2
    { float _r = -S * xi[10]; xi[10] = S * xr[10]; xr[10] = _r; }   // p=4: *(0,S)
    TMUL(14, -R2, S * R2)     // p=6
    TMUL(7,  S1,  S * C1)     // p=3
    TMUL(11, -R2, S * R2)     // p=6
    TMUL(15, -C1, -S * S1)    // p=9
    #undef TMUL

    // layer B: for each k0, DFT4 over n0 at slots 4*k0 + n0 -> X[4*k1+k0] at 4*k0+k1
    #pragma unroll
    for (int k0 = 0; k0 < 4; ++k0)
        dft4<S>(xr[4*k0], xi[4*k0], xr[4*k0+1], xi[4*k0+1],
                xr[4*k0+2], xi[4*k0+2], xr[4*k0+3], xi[4*k0+3]);

    // permute so slot q holds X[q]  (pure register renaming after full unroll)
    float tr[16], ti[16];
    #pragma unroll
    for (int q = 0; q < 16; ++q) { int p = 4*(q & 3) + (q >> 2); tr[q] = xr[p]; ti[q] = xi[p]; }
    #pragma unroll
    for (int q = 0; q < 16; ++q) { xr[q] = tr[q]; xi[q] = ti[q]; }
}

// -------------------- 4096-point FFT in LDS, radix-16, 3 stages --------------
// T0 layout: T0[p*256 + j] = e^{-2*pi*i*j*(p+1)/4096}, p in [0,15), j in [0,256).
// Stage twiddles for inverse are conjugated at use.
// Caller stages data at lds[PAD(tid + 256*r)] (same set the thread reads - no
// barrier needed before the call). On return LDS holds the transform in
// NATURAL order at PAD(t), and a trailing barrier has been issued.
template<int S>
__device__ void fft4096_r16(float2* lds, int tid, const float2* __restrict__ T0) {
    float xr[16], xi[16];

    // ---- stage 0: M=256, j=tid ----
    #pragma unroll
    for (int q = 0; q < 16; ++q) {
        float2 v = lds[PAD(tid + 256 * q)];
        xr[q] = v.x; xi[q] = v.y;
    }
    dft16<S>(xr, xi);
    #pragma unroll
    for (int q = 1; q < 16; ++q) {
        float2 w = T0[(q - 1) * 256 + tid];
        float wi = (S > 0) ? -w.y : w.y;
        float r = xr[q] * w.x - xi[q] * wi;
        xi[q] = xr[q] * wi + xi[q] * w.x;
        xr[q] = r;
    }
    #pragma unroll
    for (int q = 0; q < 16; ++q) lds[PAD(tid + 256 * q)] = make_float2(xr[q], xi[q]);
    __syncthreads();

    // ---- stage 1: M=16, j=tid&15, base=(tid>>4)*256 + j ----
    {
        const int j = tid & 15;
        const int base = ((tid >> 4) << 8) + j;
        #pragma unroll
        for (int q = 0; q < 16; ++q) {
            float2 v = lds[PAD(base + 16 * q)];
            xr[q] = v.x; xi[q] = v.y;
        }
        dft16<S>(xr, xi);
        #pragma unroll
        for (int q = 1; q < 16; ++q) {
            float2 w = T0[(q - 1) * 256 + (j << 4)];   // W_256^{j*q} = W_4096^{16*j*q}
            float wi = (S > 0) ? -w.y : w.y;
            float r = xr[q] * w.x - xi[q] * wi;
            xi[q] = xr[q] * wi + xi[q] * w.x;
            xr[q] = r;
        }
        #pragma unroll
        for (int q = 0; q < 16; ++q) lds[PAD(base + 16 * q)] = make_float2(xr[q], xi[q]);
    }
    __syncthreads();

    // ---- stage 2: M=1, base=tid*16, twiddle-free; scatter to natural order ----
    {
        const int base = tid << 4;
        const float2* src = lds + PAD(base);     // 16 contiguous float2 (pad-safe)
        #pragma unroll
        for (int q = 0; q < 16; ++q) { float2 v = src[q]; xr[q] = v.x; xi[q] = v.y; }
        dft16<S>(xr, xi);
        __syncthreads();                         // reads done before cross-scatter
        const int lo = (tid & 15) << 4;
        const int hi = tid >> 4;
        #pragma unroll
        for (int q = 0; q < 16; ++q)
            lds[PAD(q * 256 + lo + hi)] = make_float2(xr[q], xi[q]);
    }
    __syncthreads();
}

// -------------------- tables --------------------
// tw[k] = e^{-2*pi*i*k/8192}; T0 as documented above. Double-precision init.
__global__ __launch_bounds__(256) void table_init(float2* tw, float2* T0) {
    int i = blockIdx.x * 256 + threadIdx.x;
    if (i < NN) {
        double a = (-2.0 * 3.141592653589793238 / (double)NN) * (double)i;
        tw[i] = make_float2((float)cos(a), (float)sin(a));
    }
    if (i < 15 * 256) {
        int p = i >> 8, j = i & 255;
        double a = (-2.0 * 3.141592653589793238 / (double)NF) * (double)(j * (p + 1));
        T0[i] = make_float2((float)cos(a), (float)sin(a));
    }
}

__device__ __forceinline__ int refl(int p) {
    if (p < 2048) return 2047 - p;
    if (p < 6144) return p - 2048;
    return 10239 - p;
}

// -------------------- forward: real-8192 FFT via packed complex-4096 ---------
// Writes F[b][i] = X[i+1], i in [0,4096).
__global__ __launch_bounds__(256, 4) void fwd_kernel(const float* __restrict__ in,
                                                     float2* __restrict__ F,
                                                     const float2* __restrict__ tw,
                                                     const float2* __restrict__ T0) {
    __shared__ float2 lds[LDSN];
    const int b = blockIdx.x, tid = threadIdx.x;
    const float* row = in + b * TT;

    for (int i = tid; i < NF; i += 256)
        lds[PAD(i)] = make_float2(row[refl(2 * i)], row[refl(2 * i + 1)]);

    fft4096_r16<-1>(lds, tid, T0);

    for (int i = tid; i < NF; i += 256) {
        const int k = i + 1;
        const float2 za = lds[PAD(k & (NF - 1))];
        const float2 zb = lds[PAD((NF - k) & (NF - 1))];
        const float fer = 0.5f * (za.x + zb.x), fei = 0.5f * (za.y - zb.y);
        const float fo_r = 0.5f * (za.y + zb.y), fo_i = -0.5f * (za.x - zb.x);
        const float2 t = tw[k];
        F[b * NF + i] = make_float2(fer + t.x * fo_r - t.y * fo_i,
                                    fei + t.x * fo_i + t.y * fo_r);
    }
}

// -------------------- inverse: one block per (batch, scale) ------------------
// d_k = F[b,k]*wft[j,k+1]; half-band 8192-IFFT = two 4096-IFFTs (even/odd).
__global__ __launch_bounds__(256, 4) void inv_kernel(const float2* __restrict__ F,
                                                     const float* __restrict__ wft,
                                                     float* __restrict__ out,
                                                     const float2* __restrict__ tw,
                                                     const float2* __restrict__ T0,
                                                     int NS) {
    __shared__ float2 lds[LDSN];
    const int blk = blockIdx.x;
    const int b = blk / NS;
    const int j = blk - b * NS;
    const int tid = threadIdx.x;

    const float2* Frow = F + b * NF;
    const float* wrow = wft + (size_t)j * NN + 1;
    float* orow = out + (size_t)(b * NS + j) * TT;
    const float LOGN = 9.0109131020007136f;   // log(8192)

    float v0[8];
    #pragma unroll
    for (int pass = 0; pass < 2; ++pass) {
        __syncthreads();     // previous pass epilogue reads must drain
        #pragma unroll
        for (int r = 0; r < 16; ++r) {
            const int k = tid + 256 * r;
            const float2 f = Frow[k];
            const float w = wrow[k];
            float2 d = make_float2(f.x * w, f.y * w);
            if (pass) {      // * e^{+2*pi*i*k/8192} = * conj(tw[k])
                const float2 t = tw[k];
                d = make_float2(d.x * t.x + d.y * t.y, d.y * t.x - d.x * t.y);
            }
            lds[PAD(k)] = d;
        }
        fft4096_r16<1>(lds, tid, T0);

        #pragma unroll
        for (int i2 = 0; i2 < 8; ++i2) {
            const int tp = 1024 + tid + 256 * i2;   // t_global = 2*tp+pass in [2048,6144)
            const float2 z = lds[PAD(tp)];
            const float val = 0.5f * logf(z.x * z.x + z.y * z.y) - LOGN;
            if (pass == 0) v0[i2] = val;
            else ((float2*)orow)[tid + 256 * i2] = make_float2(v0[i2], val);
        }
    }
}

extern "C" void kernel_launch(void* const* d_in, const int* in_sizes, int n_in,
                              void* d_out, int out_size, void* d_ws, size_t ws_size,
                              hipStream_t stream) {
    const float* inputs = (const float*)d_in[0];
    const float* wft = (const float*)d_in[1];
    float* out = (float*)d_out;

    const int B = in_sizes[0] / TT;     // 64
    const int NS = in_sizes[1] / NN;    // 75

    float2* F = (float2*)d_ws;                                          // 2 MB
    float2* tw = (float2*)((char*)d_ws + (size_t)B * NF * sizeof(float2));
    float2* T0 = tw + NN;                                               // 30 KB

    hipLaunchKernelGGL(table_init, dim3(32), dim3(256), 0, stream, tw, T0);
    hipLaunchKernelGGL(fwd_kernel, dim3(B), dim3(256), 0, stream, inputs, F, tw, T0);
    hipLaunchKernelGGL(inv_kernel, dim3(B * NS), dim3(256), 0, stream, F, wft, out, tw, T0, NS);
}

// Round 3
// 260.221 us; speedup vs baseline: 1.2959x; 1.2959x over previous
//
#include <hip/hip_runtime.h>
#include <math.h>

#define TT 4096          // signal length
#define NN 8192          // padded length
#define NF 4096          // FFT length = 16^3
#define PAD(i) ((i) + 3 * ((i) >> 5))
#define LDSN 4480        // PAD(4095)=4476, rounded up; float2 -> 35840 B

// -------------------- register DFT16 (two radix-4 layers, DIT) --------------
// S = -1: forward (e^{-i}), S = +1: inverse (e^{+i}).
template<int S>
__device__ __forceinline__ void dft4(float& ar, float& ai, float& br, float& bi,
                                     float& cr, float& ci, float& er, float& ei) {
    float t0r = ar + cr, t0i = ai + ci;
    float t1r = ar - cr, t1i = ai - ci;
    float t2r = br + er, t2i = bi + ei;
    float t3r = br - er, t3i = bi - ei;
    ar = t0r + t2r; ai = t0i + t2i;
    cr = t0r - t2r; ci = t0i - t2i;
    // y1 = t1 + S*i*t3, y3 = t1 - S*i*t3
    br = t1r - S * t3i; bi = t1i + S * t3r;
    er = t1r + S * t3i; ei = t1i - S * t3r;
}

template<int S>
__device__ __forceinline__ void dft16(float xr[16], float xi[16]) {
    // layer A: DFT4 over n1 of x[n0 + 4*n1]; result A_{n0}[k0] lands at n0 + 4*k0
    #pragma unroll
    for (int n0 = 0; n0 < 4; ++n0)
        dft4<S>(xr[n0], xi[n0], xr[n0 + 4], xi[n0 + 4],
                xr[n0 + 8], xi[n0 + 8], xr[n0 + 12], xi[n0 + 12]);

    const float C1 = 0.9238795325112867f;   // cos(pi/8)
    const float S1 = 0.3826834323650898f;   // sin(pi/8)
    const float R2 = 0.7071067811865476f;
    // B_{n0}[k0] = A * W16^{S-signed n0*k0}; W^p = (cos, S*sin), theta = 2*pi*p/16
    #define TMUL(idx, wr, wi) { float _r = xr[idx]*(wr) - xi[idx]*(wi); \
                                xi[idx] = xr[idx]*(wi) + xi[idx]*(wr); xr[idx] = _r; }
    TMUL(5,  C1,  S * S1)     // p=1
    TMUL(9,  R2,  S * R2)     // p=2
    TMUL(13, S1,  S * C1)     // p=3
    TMUL(6,  R2,  S * R2)     // p=2
    { float _r = -S * xi[10]; xi[10] = S * xr[10]; xr[10] = _r; }   // p=4: *(0,S)
    TMUL(14, -R2, S * R2)     // p=6
    TMUL(7,  S1,  S * C1)     // p=3
    TMUL(11, -R2, S * R2)     // p=6
    TMUL(15, -C1, -S * S1)    // p=9
    #undef TMUL

    // layer B: for each k0, DFT4 over n0 at slots 4*k0 + n0 -> X[4*k1+k0] at 4*k0+k1
    #pragma unroll
    for (int k0 = 0; k0 < 4; ++k0)
        dft4<S>(xr[4*k0], xi[4*k0], xr[4*k0+1], xi[4*k0+1],
                xr[4*k0+2], xi[4*k0+2], xr[4*k0+3], xi[4*k0+3]);

    // permute so slot q holds X[q]  (pure register renaming after full unroll)
    float tr[16], ti[16];
    #pragma unroll
    for (int q = 0; q < 16; ++q) { int p = 4*(q & 3) + (q >> 2); tr[q] = xr[p]; ti[q] = xi[p]; }
    #pragma unroll
    for (int q = 0; q < 16; ++q) { xr[q] = tr[q]; xi[q] = ti[q]; }
}

// -------------------- 4096-point FFT in LDS, radix-16, 3 stages --------------
// T0 layout: T0[p*256 + j] = e^{-2*pi*i*j*(p+1)/4096}, p in [0,15), j in [0,256).
// Stage twiddles for inverse are conjugated at use.
// Caller stages data at lds[PAD(tid + 256*r)] (same set the thread reads - no
// barrier needed before the call). On return LDS holds the transform in
// NATURAL order at PAD(t), and a trailing barrier has been issued.
template<int S>
__device__ void fft4096_r16(float2* lds, int tid, const float2* __restrict__ T0) {
    float xr[16], xi[16];

    // ---- stage 0: M=256, j=tid ----
    #pragma unroll
    for (int q = 0; q < 16; ++q) {
        float2 v = lds[PAD(tid + 256 * q)];
        xr[q] = v.x; xi[q] = v.y;
    }
    dft16<S>(xr, xi);
    #pragma unroll
    for (int q = 1; q < 16; ++q) {
        float2 w = T0[(q - 1) * 256 + tid];
        float wi = (S > 0) ? -w.y : w.y;
        float r = xr[q] * w.x - xi[q] * wi;
        xi[q] = xr[q] * wi + xi[q] * w.x;
        xr[q] = r;
    }
    #pragma unroll
    for (int q = 0; q < 16; ++q) lds[PAD(tid + 256 * q)] = make_float2(xr[q], xi[q]);
    __syncthreads();

    // ---- stage 1: M=16, j=tid&15, base=(tid>>4)*256 + j ----
    {
        const int j = tid & 15;
        const int base = ((tid >> 4) << 8) + j;
        #pragma unroll
        for (int q = 0; q < 16; ++q) {
            float2 v = lds[PAD(base + 16 * q)];
            xr[q] = v.x; xi[q] = v.y;
        }
        dft16<S>(xr, xi);
        #pragma unroll
        for (int q = 1; q < 16; ++q) {
            float2 w = T0[(q - 1) * 256 + (j << 4)];   // W_256^{j*q} = W_4096^{16*j*q}
            float wi = (S > 0) ? -w.y : w.y;
            float r = xr[q] * w.x - xi[q] * wi;
            xi[q] = xr[q] * wi + xi[q] * w.x;
            xr[q] = r;
        }
        #pragma unroll
        for (int q = 0; q < 16; ++q) lds[PAD(base + 16 * q)] = make_float2(xr[q], xi[q]);
    }
    __syncthreads();

    // ---- stage 2: M=1, base=tid*16, twiddle-free; scatter to natural order ----
    {
        const int base = tid << 4;
        const float2* src = lds + PAD(base);     // 16 contiguous float2 (pad-safe)
        #pragma unroll
        for (int q = 0; q < 16; ++q) { float2 v = src[q]; xr[q] = v.x; xi[q] = v.y; }
        dft16<S>(xr, xi);
        __syncthreads();                         // reads done before cross-scatter
        const int lo = (tid & 15) << 4;
        const int hi = tid >> 4;
        #pragma unroll
        for (int q = 0; q < 16; ++q)
            lds[PAD(q * 256 + lo + hi)] = make_float2(xr[q], xi[q]);
    }
    __syncthreads();
}

// -------------------- tables --------------------
// tw[k] = e^{-2*pi*i*k/8192}; T0 as documented above. Double-precision init.
__global__ __launch_bounds__(256) void table_init(float2* tw, float2* T0) {
    int i = blockIdx.x * 256 + threadIdx.x;
    if (i < NN) {
        double a = (-2.0 * 3.141592653589793238 / (double)NN) * (double)i;
        tw[i] = make_float2((float)cos(a), (float)sin(a));
    }
    if (i < 15 * 256) {
        int p = i >> 8, j = i & 255;
        double a = (-2.0 * 3.141592653589793238 / (double)NF) * (double)(j * (p + 1));
        T0[i] = make_float2((float)cos(a), (float)sin(a));
    }
}

__device__ __forceinline__ int refl(int p) {
    if (p < 2048) return 2047 - p;
    if (p < 6144) return p - 2048;
    return 10239 - p;
}

// -------------------- forward: real-8192 FFT via packed complex-4096 ---------
// Writes F[b][i] = X[i+1], i in [0,4096).
__global__ __launch_bounds__(256) void fwd_kernel(const float* __restrict__ in,
                                                  float2* __restrict__ F,
                                                  const float2* __restrict__ tw,
                                                  const float2* __restrict__ T0) {
    __shared__ float2 lds[LDSN];
    const int b = blockIdx.x, tid = threadIdx.x;
    const float* row = in + b * TT;

    for (int i = tid; i < NF; i += 256)
        lds[PAD(i)] = make_float2(row[refl(2 * i)], row[refl(2 * i + 1)]);

    fft4096_r16<-1>(lds, tid, T0);

    for (int i = tid; i < NF; i += 256) {
        const int k = i + 1;
        const float2 za = lds[PAD(k & (NF - 1))];
        const float2 zb = lds[PAD((NF - k) & (NF - 1))];
        const float fer = 0.5f * (za.x + zb.x), fei = 0.5f * (za.y - zb.y);
        const float fo_r = 0.5f * (za.y + zb.y), fo_i = -0.5f * (za.x - zb.x);
        const float2 t = tw[k];
        F[b * NF + i] = make_float2(fer + t.x * fo_r - t.y * fo_i,
                                    fei + t.x * fo_i + t.y * fo_r);
    }
}

// -------------------- inverse: one block per (batch, scale) ------------------
// d_k = F[b,k]*wft[j,k+1]; half-band 8192-IFFT = two 4096-IFFTs (even/odd).
__global__ __launch_bounds__(256) void inv_kernel(const float2* __restrict__ F,
                                                  const float* __restrict__ wft,
                                                  float* __restrict__ out,
                                                  const float2* __restrict__ tw,
                                                  const float2* __restrict__ T0,
                                                  int NS) {
    __shared__ float2 lds[LDSN];
    const int blk = blockIdx.x;
    const int b = blk / NS;
    const int j = blk - b * NS;
    const int tid = threadIdx.x;

    const float2* Frow = F + b * NF;
    const float* wrow = wft + (size_t)j * NN + 1;
    float* orow = out + (size_t)(b * NS + j) * TT;
    const float LOGN = 9.0109131020007136f;   // log(8192)

    float v0[8];
    #pragma unroll
    for (int pass = 0; pass < 2; ++pass) {
        __syncthreads();     // previous pass epilogue reads must drain
        #pragma unroll
        for (int r = 0; r < 16; ++r) {
            const int k = tid + 256 * r;
            const float2 f = Frow[k];
            const float w = wrow[k];
            float2 d = make_float2(f.x * w, f.y * w);
            if (pass) {      // * e^{+2*pi*i*k/8192} = * conj(tw[k])
                const float2 t = tw[k];
                d = make_float2(d.x * t.x + d.y * t.y, d.y * t.x - d.x * t.y);
            }
            lds[PAD(k)] = d;
        }
        fft4096_r16<1>(lds, tid, T0);

        #pragma unroll
        for (int i2 = 0; i2 < 8; ++i2) {
            const int tp = 1024 + tid + 256 * i2;   // t_global = 2*tp+pass in [2048,6144)
            const float2 z = lds[PAD(tp)];
            const float val = 0.5f * logf(z.x * z.x + z.y * z.y) - LOGN;
            if (pass == 0) v0[i2] = val;
            else ((float2*)orow)[tid + 256 * i2] = make_float2(v0[i2], val);
        }
    }
}

extern "C" void kernel_launch(void* const* d_in, const int* in_sizes, int n_in,
                              void* d_out, int out_size, void* d_ws, size_t ws_size,
                              hipStream_t stream) {
    const float* inputs = (const float*)d_in[0];
    const float* wft = (const float*)d_in[1];
    float* out = (float*)d_out;

    const int B = in_sizes[0] / TT;     // 64
    const int NS = in_sizes[1] / NN;    // 75

    float2* F = (float2*)d_ws;                                          // 2 MB
    float2* tw = (float2*)((char*)d_ws + (size_t)B * NF * sizeof(float2));
    float2* T0 = tw + NN;                                               // 30 KB

    hipLaunchKernelGGL(table_init, dim3(32), dim3(256), 0, stream, tw, T0);
    hipLaunchKernelGGL(fwd_kernel, dim3(B), dim3(256), 0, stream, inputs, F, tw, T0);
    hipLaunchKernelGGL(inv_kernel, dim3(B * NS), dim3(256), 0, stream, F, wft, out, tw, T0, NS);
}

// Round 4
// 173.636 us; speedup vs baseline: 1.9421x; 1.4987x over previous
//
#include <hip/hip_runtime.h>

#define TT 4096          // signal length
#define NN 8192          // padded length
#define NF 4096          // FFT length = 16^3

// XOR swizzle: permutes low 4 bits by a hash of the row -> every wave64 b64
// access in this kernel hits each bank-pair exactly 4x (HW minimum).
// Array size stays exactly 4096 float2 = 32768 B -> 5 blocks/CU.
#define SW(i) ((i) ^ ((((i) >> 4) ^ ((i) >> 8)) & 15))

// hardware sin/cos of 2*pi*x (x in revolutions); args here are exact dyadics
__device__ __forceinline__ float sin2pi(float x) { return __builtin_amdgcn_sinf(x); }
__device__ __forceinline__ float cos2pi(float x) { return __builtin_amdgcn_cosf(x); }

// -------------------- register DFT16 (two radix-4 layers, DIT) --------------
// S = -1: forward (e^{-i}), S = +1: inverse (e^{+i}).
template<int S>
__device__ __forceinline__ void dft4(float& ar, float& ai, float& br, float& bi,
                                     float& cr, float& ci, float& er, float& ei) {
    float t0r = ar + cr, t0i = ai + ci;
    float t1r = ar - cr, t1i = ai - ci;
    float t2r = br + er, t2i = bi + ei;
    float t3r = br - er, t3i = bi - ei;
    ar = t0r + t2r; ai = t0i + t2i;
    cr = t0r - t2r; ci = t0i - t2i;
    br = t1r - S * t3i; bi = t1i + S * t3r;
    er = t1r + S * t3i; ei = t1i - S * t3r;
}

template<int S>
__device__ __forceinline__ void dft16(float xr[16], float xi[16]) {
    #pragma unroll
    for (int n0 = 0; n0 < 4; ++n0)
        dft4<S>(xr[n0], xi[n0], xr[n0 + 4], xi[n0 + 4],
                xr[n0 + 8], xi[n0 + 8], xr[n0 + 12], xi[n0 + 12]);

    const float C1 = 0.9238795325112867f;   // cos(pi/8)
    const float S1 = 0.3826834323650898f;   // sin(pi/8)
    const float R2 = 0.7071067811865476f;
    #define TMUL(idx, wr, wi) { float _r = xr[idx]*(wr) - xi[idx]*(wi); \
                                xi[idx] = xr[idx]*(wi) + xi[idx]*(wr); xr[idx] = _r; }
    TMUL(5,  C1,  S * S1)
    TMUL(9,  R2,  S * R2)
    TMUL(13, S1,  S * C1)
    TMUL(6,  R2,  S * R2)
    { float _r = -S * xi[10]; xi[10] = S * xr[10]; xr[10] = _r; }
    TMUL(14, -R2, S * R2)
    TMUL(7,  S1,  S * C1)
    TMUL(11, -R2, S * R2)
    TMUL(15, -C1, -S * S1)
    #undef TMUL

    #pragma unroll
    for (int k0 = 0; k0 < 4; ++k0)
        dft4<S>(xr[4*k0], xi[4*k0], xr[4*k0+1], xi[4*k0+1],
                xr[4*k0+2], xi[4*k0+2], xr[4*k0+3], xi[4*k0+3]);

    float tr[16], ti[16];
    #pragma unroll
    for (int q = 0; q < 16; ++q) { int p = 4*(q & 3) + (q >> 2); tr[q] = xr[p]; ti[q] = xi[p]; }
    #pragma unroll
    for (int q = 0; q < 16; ++q) { xr[q] = tr[q]; xi[q] = ti[q]; }
}

// -------------------- 4096-point FFT in LDS, radix-16, 3 stages --------------
// All twiddles generated by v_sin/v_cos (exact dyadic arguments, no tables).
// Caller stages data at lds[SW(tid + 256*r)] (the same set this thread reads
// in stage 0 - no barrier needed before the call). On return LDS holds the
// transform in NATURAL order at SW(t); trailing barrier already issued.
template<int S>
__device__ void fft4096_r16(float2* lds, int tid) {
    float xr[16], xi[16];

    // ---- stage 0: stride 256, j = tid, twiddle W_4096^{j*q} ----
    #pragma unroll
    for (int q = 0; q < 16; ++q) {
        float2 v = lds[SW(tid + 256 * q)];
        xr[q] = v.x; xi[q] = v.y;
    }
    dft16<S>(xr, xi);
    #pragma unroll
    for (int q = 1; q < 16; ++q) {
        const float t = (float)(tid * q) * (1.0f / 4096.0f);
        const float wr = cos2pi(t), wi = S * sin2pi(t);   // e^{-S? }: (c, S*s)
        float r = xr[q] * wr - xi[q] * wi;
        xi[q] = xr[q] * wi + xi[q] * wr;
        xr[q] = r;
    }
    #pragma unroll
    for (int q = 0; q < 16; ++q) lds[SW(tid + 256 * q)] = make_float2(xr[q], xi[q]);
    __syncthreads();

    // ---- stage 1: stride 16, j = tid&15, twiddle W_256^{j*q} ----
    {
        const int j = tid & 15;
        const int base = ((tid >> 4) << 8) + j;
        #pragma unroll
        for (int q = 0; q < 16; ++q) {
            float2 v = lds[SW(base + 16 * q)];
            xr[q] = v.x; xi[q] = v.y;
        }
        dft16<S>(xr, xi);
        #pragma unroll
        for (int q = 1; q < 16; ++q) {
            const float t = (float)(j * q) * (1.0f / 256.0f);
            const float wr = cos2pi(t), wi = S * sin2pi(t);
            float r = xr[q] * wr - xi[q] * wi;
            xi[q] = xr[q] * wi + xi[q] * wr;
            xr[q] = r;
        }
        #pragma unroll
        for (int q = 0; q < 16; ++q) lds[SW(base + 16 * q)] = make_float2(xr[q], xi[q]);
    }
    __syncthreads();

    // ---- stage 2: 16 contiguous points per thread, twiddle-free; ----
    // ---- scatter result to natural order ----
    {
        const int base = tid << 4;
        const int f2 = (tid ^ (tid >> 4)) & 15;     // SW low-4 perm for this row
        #pragma unroll
        for (int q = 0; q < 16; ++q) {
            float2 v = lds[base + (q ^ f2)];
            xr[q] = v.x; xi[q] = v.y;
        }
        dft16<S>(xr, xi);
        __syncthreads();                            // reads done before scatter
        const int c = tid & 15;
        const int h = tid >> 4;
        #pragma unroll
        for (int q = 0; q < 16; ++q)
            lds[(q << 8) + (c << 4) + (h ^ c ^ q)] = make_float2(xr[q], xi[q]);
    }
    __syncthreads();
}

__device__ __forceinline__ int refl(int p) {
    if (p < 2048) return 2047 - p;
    if (p < 6144) return p - 2048;
    return 10239 - p;
}

// -------------------- forward: real-8192 FFT via packed complex-4096 ---------
// Writes F[b][i] = X[i+1], i in [0,4096).
__global__ __launch_bounds__(256) void fwd_kernel(const float* __restrict__ in,
                                                  float2* __restrict__ F) {
    __shared__ float2 lds[NF];
    const int b = blockIdx.x, tid = threadIdx.x;
    const float* row = in + b * TT;

    for (int i = tid; i < NF; i += 256)
        lds[SW(i)] = make_float2(row[refl(2 * i)], row[refl(2 * i + 1)]);

    fft4096_r16<-1>(lds, tid);

    for (int i = tid; i < NF; i += 256) {
        const int k = i + 1;
        const float2 za = lds[SW(k & (NF - 1))];
        const float2 zb = lds[SW((NF - k) & (NF - 1))];
        const float fer = 0.5f * (za.x + zb.x), fei = 0.5f * (za.y - zb.y);
        const float fo_r = 0.5f * (za.y + zb.y), fo_i = -0.5f * (za.x - zb.x);
        const float t = (float)k * (1.0f / 8192.0f);
        const float c = cos2pi(t), s = sin2pi(t);   // tw = (c, -s)
        F[b * NF + i] = make_float2(fer + c * fo_r + s * fo_i,
                                    fei + c * fo_i - s * fo_r);
    }
}

// -------------------- inverse: one block per (batch, scale) ------------------
// d_k = F[b,k]*wft[j,k+1]; half-band 8192-IFFT = two 4096-IFFTs (even/odd).
__global__ __launch_bounds__(256) void inv_kernel(const float2* __restrict__ F,
                                                  const float* __restrict__ wft,
                                                  float* __restrict__ out,
                                                  int NS) {
    __shared__ float2 lds[NF];
    const int blk = blockIdx.x;
    const int b = blk / NS;
    const int j = blk - b * NS;
    const int tid = threadIdx.x;

    const float2* Frow = F + b * NF;
    const float* wrow = wft + (size_t)j * NN + 1;
    float* orow = out + (size_t)(b * NS + j) * TT;
    const float LOGN = 9.0109131020007136f;    // log(8192)
    const float HALF_LN2 = 0.34657359027997264f;  // 0.5 * ln(2)

    float v0[8];
    #pragma unroll
    for (int pass = 0; pass < 2; ++pass) {
        __syncthreads();     // previous pass epilogue reads must drain
        #pragma unroll
        for (int r = 0; r < 16; ++r) {
            const int k = tid + 256 * r;
            const float2 f = Frow[k];
            const float w = wrow[k];
            float2 d = make_float2(f.x * w, f.y * w);
            if (pass) {      // * e^{+2*pi*i*k/8192}
                const float t = (float)k * (1.0f / 8192.0f);
                const float c = cos2pi(t), s = sin2pi(t);
                d = make_float2(d.x * c - d.y * s, d.x * s + d.y * c);
            }
            lds[SW(k)] = d;
        }
        fft4096_r16<1>(lds, tid);

        #pragma unroll
        for (int i2 = 0; i2 < 8; ++i2) {
            const int tp = 1024 + tid + 256 * i2;   // t_global = 2*tp+pass
            const float2 z = lds[SW(tp)];
            const float m = z.x * z.x + z.y * z.y;
            const float val = HALF_LN2 * __builtin_amdgcn_logf(m) - LOGN;
            if (pass == 0) v0[i2] = val;
            else ((float2*)orow)[tid + 256 * i2] = make_float2(v0[i2], val);
        }
    }
}

extern "C" void kernel_launch(void* const* d_in, const int* in_sizes, int n_in,
                              void* d_out, int out_size, void* d_ws, size_t ws_size,
                              hipStream_t stream) {
    const float* inputs = (const float*)d_in[0];
    const float* wft = (const float*)d_in[1];
    float* out = (float*)d_out;

    const int B = in_sizes[0] / TT;     // 64
    const int NS = in_sizes[1] / NN;    // 75

    float2* F = (float2*)d_ws;          // B*4096 complex = 2 MB

    hipLaunchKernelGGL(fwd_kernel, dim3(B), dim3(256), 0, stream, inputs, F);
    hipLaunchKernelGGL(inv_kernel, dim3(B * NS), dim3(256), 0, stream, F, wft, out, NS);
}

// Round 5
// 161.129 us; speedup vs baseline: 2.0929x; 1.0776x over previous
//
#include <hip/hip_runtime.h>

#define TT 4096          // signal length
#define NN 8192          // padded length
#define NF 4096          // FFT length = 16^3

// XOR swizzle: permutes low 4 bits by a hash of the row; measured ~2% LDS
// bank-conflict overhead in R4 across all access patterns used here.
#define SW(i) ((i) ^ ((((i) >> 4) ^ ((i) >> 8)) & 15))

// hardware sin/cos of 2*pi*x (x in revolutions); args here are exact dyadics
__device__ __forceinline__ float sin2pi(float x) { return __builtin_amdgcn_sinf(x); }
__device__ __forceinline__ float cos2pi(float x) { return __builtin_amdgcn_cosf(x); }

// -------------------- register DFT16 (two radix-4 layers, DIT) --------------
// S = -1: forward (e^{-i}), S = +1: inverse (e^{+i}).
template<int S>
__device__ __forceinline__ void dft4(float& ar, float& ai, float& br, float& bi,
                                     float& cr, float& ci, float& er, float& ei) {
    float t0r = ar + cr, t0i = ai + ci;
    float t1r = ar - cr, t1i = ai - ci;
    float t2r = br + er, t2i = bi + ei;
    float t3r = br - er, t3i = bi - ei;
    ar = t0r + t2r; ai = t0i + t2i;
    cr = t0r - t2r; ci = t0i - t2i;
    br = t1r - S * t3i; bi = t1i + S * t3r;
    er = t1r + S * t3i; ei = t1i - S * t3r;
}

template<int S>
__device__ __forceinline__ void dft16(float xr[16], float xi[16]) {
    #pragma unroll
    for (int n0 = 0; n0 < 4; ++n0)
        dft4<S>(xr[n0], xi[n0], xr[n0 + 4], xi[n0 + 4],
                xr[n0 + 8], xi[n0 + 8], xr[n0 + 12], xi[n0 + 12]);

    const float C1 = 0.9238795325112867f;   // cos(pi/8)
    const float S1 = 0.3826834323650898f;   // sin(pi/8)
    const float R2 = 0.7071067811865476f;
    #define TMUL(idx, wr, wi) { float _r = xr[idx]*(wr) - xi[idx]*(wi); \
                                xi[idx] = xr[idx]*(wi) + xi[idx]*(wr); xr[idx] = _r; }
    TMUL(5,  C1,  S * S1)
    TMUL(9,  R2,  S * R2)
    TMUL(13, S1,  S * C1)
    TMUL(6,  R2,  S * R2)
    { float _r = -S * xi[10]; xi[10] = S * xr[10]; xr[10] = _r; }
    TMUL(14, -R2, S * R2)
    TMUL(7,  S1,  S * C1)
    TMUL(11, -R2, S * R2)
    TMUL(15, -C1, -S * S1)
    #undef TMUL

    #pragma unroll
    for (int k0 = 0; k0 < 4; ++k0)
        dft4<S>(xr[4*k0], xi[4*k0], xr[4*k0+1], xi[4*k0+1],
                xr[4*k0+2], xi[4*k0+2], xr[4*k0+3], xi[4*k0+3]);

    float tr[16], ti[16];
    #pragma unroll
    for (int q = 0; q < 16; ++q) { int p = 4*(q & 3) + (q >> 2); tr[q] = xr[p]; ti[q] = xi[p]; }
    #pragma unroll
    for (int q = 0; q < 16; ++q) { xr[q] = tr[q]; xi[q] = ti[q]; }
}

// ==================== single-signal FFT (fwd kernel) =========================
template<int S>
__device__ void fft4096_r16(float2* lds, int tid) {
    float xr[16], xi[16];

    #pragma unroll
    for (int q = 0; q < 16; ++q) {
        float2 v = lds[SW(tid + 256 * q)];
        xr[q] = v.x; xi[q] = v.y;
    }
    dft16<S>(xr, xi);
    #pragma unroll
    for (int q = 1; q < 16; ++q) {
        const float t = (float)(tid * q) * (1.0f / 4096.0f);
        const float wr = cos2pi(t), wi = S * sin2pi(t);
        float r = xr[q] * wr - xi[q] * wi;
        xi[q] = xr[q] * wi + xi[q] * wr;
        xr[q] = r;
    }
    #pragma unroll
    for (int q = 0; q < 16; ++q) lds[SW(tid + 256 * q)] = make_float2(xr[q], xi[q]);
    __syncthreads();

    {
        const int j = tid & 15;
        const int base = ((tid >> 4) << 8) + j;
        #pragma unroll
        for (int q = 0; q < 16; ++q) {
            float2 v = lds[SW(base + 16 * q)];
            xr[q] = v.x; xi[q] = v.y;
        }
        dft16<S>(xr, xi);
        #pragma unroll
        for (int q = 1; q < 16; ++q) {
            const float t = (float)(j * q) * (1.0f / 256.0f);
            const float wr = cos2pi(t), wi = S * sin2pi(t);
            float r = xr[q] * wr - xi[q] * wi;
            xi[q] = xr[q] * wi + xi[q] * wr;
            xr[q] = r;
        }
        #pragma unroll
        for (int q = 0; q < 16; ++q) lds[SW(base + 16 * q)] = make_float2(xr[q], xi[q]);
    }
    __syncthreads();

    {
        const int base = tid << 4;
        const int f2 = (tid ^ (tid >> 4)) & 15;
        #pragma unroll
        for (int q = 0; q < 16; ++q) {
            float2 v = lds[base + (q ^ f2)];
            xr[q] = v.x; xi[q] = v.y;
        }
        dft16<S>(xr, xi);
        __syncthreads();
        const int c = tid & 15;
        const int h = tid >> 4;
        #pragma unroll
        for (int q = 0; q < 16; ++q)
            lds[(q << 8) + (c << 4) + (h ^ c ^ q)] = make_float2(xr[q], xi[q]);
    }
    __syncthreads();
}

// ==================== fused 2-signal FFT (inv kernel) ========================
// lds[i] = (re0, im0, re1, im1): both IFFT passes share twiddles, DS ops,
// and barriers. Natural-order result at SW(t) on return.
template<int S>
__device__ void fft4096_r16x2(float4* lds, int tid) {
    float xr0[16], xi0[16], xr1[16], xi1[16];

    #define CMUL2(q, wr, wi) { \
        float _r0 = xr0[q]*(wr) - xi0[q]*(wi); xi0[q] = xr0[q]*(wi) + xi0[q]*(wr); xr0[q] = _r0; \
        float _r1 = xr1[q]*(wr) - xi1[q]*(wi); xi1[q] = xr1[q]*(wi) + xi1[q]*(wr); xr1[q] = _r1; }

    // ---- stage 0: stride 256, j = tid ----
    #pragma unroll
    for (int q = 0; q < 16; ++q) {
        float4 v = lds[SW(tid + 256 * q)];
        xr0[q] = v.x; xi0[q] = v.y; xr1[q] = v.z; xi1[q] = v.w;
    }
    dft16<S>(xr0, xi0);
    dft16<S>(xr1, xi1);
    #pragma unroll
    for (int q = 1; q < 16; ++q) {
        const float t = (float)(tid * q) * (1.0f / 4096.0f);
        const float wr = cos2pi(t), wi = S * sin2pi(t);
        CMUL2(q, wr, wi)
    }
    #pragma unroll
    for (int q = 0; q < 16; ++q)
        lds[SW(tid + 256 * q)] = make_float4(xr0[q], xi0[q], xr1[q], xi1[q]);
    __syncthreads();

    // ---- stage 1: stride 16, j = tid&15 ----
    {
        const int j = tid & 15;
        const int base = ((tid >> 4) << 8) + j;
        #pragma unroll
        for (int q = 0; q < 16; ++q) {
            float4 v = lds[SW(base + 16 * q)];
            xr0[q] = v.x; xi0[q] = v.y; xr1[q] = v.z; xi1[q] = v.w;
        }
        dft16<S>(xr0, xi0);
        dft16<S>(xr1, xi1);
        #pragma unroll
        for (int q = 1; q < 16; ++q) {
            const float t = (float)(j * q) * (1.0f / 256.0f);
            const float wr = cos2pi(t), wi = S * sin2pi(t);
            CMUL2(q, wr, wi)
        }
        #pragma unroll
        for (int q = 0; q < 16; ++q)
            lds[SW(base + 16 * q)] = make_float4(xr0[q], xi0[q], xr1[q], xi1[q]);
    }
    __syncthreads();

    // ---- stage 2: contiguous 16/thread, twiddle-free; scatter natural ----
    {
        const int base = tid << 4;
        const int f2 = (tid ^ (tid >> 4)) & 15;
        #pragma unroll
        for (int q = 0; q < 16; ++q) {
            float4 v = lds[base + (q ^ f2)];
            xr0[q] = v.x; xi0[q] = v.y; xr1[q] = v.z; xi1[q] = v.w;
        }
        dft16<S>(xr0, xi0);
        dft16<S>(xr1, xi1);
        __syncthreads();
        const int c = tid & 15;
        const int h = tid >> 4;
        #pragma unroll
        for (int q = 0; q < 16; ++q)
            lds[(q << 8) + (c << 4) + (h ^ c ^ q)] = make_float4(xr0[q], xi0[q], xr1[q], xi1[q]);
    }
    __syncthreads();
    #undef CMUL2
}

__device__ __forceinline__ int refl(int p) {
    if (p < 2048) return 2047 - p;
    if (p < 6144) return p - 2048;
    return 10239 - p;
}

// -------------------- forward: real-8192 FFT via packed complex-4096 ---------
__global__ __launch_bounds__(256) void fwd_kernel(const float* __restrict__ in,
                                                  float2* __restrict__ F) {
    __shared__ float2 lds[NF];
    const int b = blockIdx.x, tid = threadIdx.x;
    const float* row = in + b * TT;

    for (int i = tid; i < NF; i += 256)
        lds[SW(i)] = make_float2(row[refl(2 * i)], row[refl(2 * i + 1)]);

    fft4096_r16<-1>(lds, tid);

    for (int i = tid; i < NF; i += 256) {
        const int k = i + 1;
        const float2 za = lds[SW(k & (NF - 1))];
        const float2 zb = lds[SW((NF - k) & (NF - 1))];
        const float fer = 0.5f * (za.x + zb.x), fei = 0.5f * (za.y - zb.y);
        const float fo_r = 0.5f * (za.y + zb.y), fo_i = -0.5f * (za.x - zb.x);
        const float t = (float)k * (1.0f / 8192.0f);
        const float c = cos2pi(t), s = sin2pi(t);   // tw = (c, -s)
        F[b * NF + i] = make_float2(fer + c * fo_r + s * fo_i,
                                    fei + c * fo_i - s * fo_r);
    }
}

// -------------------- inverse: one block per (batch, scale) ------------------
// d_k = F[b,k]*wft[j,k+1]; half-band 8192-IFFT = two 4096-IFFTs computed
// TOGETHER as one 2-vector FFT (signal0 = even samples, signal1 = odd).
__global__ __launch_bounds__(256) void inv_kernel(const float2* __restrict__ F,
                                                  const float* __restrict__ wft,
                                                  float* __restrict__ out,
                                                  int NS) {
    __shared__ float4 lds[NF];                 // 64 KB -> 2 blocks/CU
    const int blk = blockIdx.x;
    const int b = blk / NS;
    const int j = blk - b * NS;
    const int tid = threadIdx.x;

    const float2* Frow = F + b * NF;
    const float* wrow = wft + (size_t)j * NN + 1;
    float* orow = out + (size_t)(b * NS + j) * TT;
    const float LOGN = 9.0109131020007136f;       // log(8192)
    const float HALF_LN2 = 0.34657359027997264f;  // 0.5 * ln(2)

    // staging: d0 = F*w ; d1 = d0 * e^{+2*pi*i*k/8192}
    #pragma unroll
    for (int r = 0; r < 16; ++r) {
        const int k = tid + 256 * r;
        const float2 f = Frow[k];
        const float w = wrow[k];
        const float d0r = f.x * w, d0i = f.y * w;
        const float t = (float)k * (1.0f / 8192.0f);
        const float c = cos2pi(t), s = sin2pi(t);
        const float d1r = d0r * c - d0i * s;
        const float d1i = d0r * s + d0i * c;
        lds[SW(k)] = make_float4(d0r, d0i, d1r, d1i);
    }

    fft4096_r16x2<1>(lds, tid);

    #pragma unroll
    for (int i2 = 0; i2 < 8; ++i2) {
        const int tp = 1024 + tid + 256 * i2;   // t_global = 2*tp+{0,1} in [2048,6144)
        const float4 z = lds[SW(tp)];
        const float m0 = z.x * z.x + z.y * z.y;
        const float m1 = z.z * z.z + z.w * z.w;
        const float v0 = HALF_LN2 * __builtin_amdgcn_logf(m0) - LOGN;
        const float v1 = HALF_LN2 * __builtin_amdgcn_logf(m1) - LOGN;
        ((float2*)orow)[tid + 256 * i2] = make_float2(v0, v1);
    }
}

extern "C" void kernel_launch(void* const* d_in, const int* in_sizes, int n_in,
                              void* d_out, int out_size, void* d_ws, size_t ws_size,
                              hipStream_t stream) {
    const float* inputs = (const float*)d_in[0];
    const float* wft = (const float*)d_in[1];
    float* out = (float*)d_out;

    const int B = in_sizes[0] / TT;     // 64
    const int NS = in_sizes[1] / NN;    // 75

    float2* F = (float2*)d_ws;          // B*4096 complex = 2 MB

    hipLaunchKernelGGL(fwd_kernel, dim3(B), dim3(256), 0, stream, inputs, F);
    hipLaunchKernelGGL(inv_kernel, dim3(B * NS), dim3(256), 0, stream, F, wft, out, NS);
}